// Round 3
// baseline (381.111 us; speedup 1.0000x reference)
//
#include <hip/hip_runtime.h>
#include <stdint.h>

typedef unsigned long long u64;
typedef unsigned int u32;

#define N_IMG 32
#define C_IN  256
#define C_OUT 256
#define H     56
#define W     56
#define HW    (H*W)          // 3136
#define NHW   (N_IMG*HW)     // 100352
#define CHW   (C_IN*HW)      // 802816

// Workspace layout:
//   px: [n][h][w][4] u64 packed sign bits of x      (401408 * 8 = 3,211,264 B)
//   pw: [co][tap(9)][4] u64                         (9216   * 8 =    73,728 B)
//   y : [n][co][h][w] int16 exact conv result       (25,690,112 * 2 = 51,380,224 B)
//   partials: overlaps px (px dead after conv) — [8192][2] long long = 131,072 B
#define PX_BYTES 3211264
#define PW_BYTES 73728

// ---------------------------------------------------------------------------
// Pack activations, 4 pixels per thread via float4. bit=1 <=> sign(x)==-1.
// ---------------------------------------------------------------------------
__global__ __launch_bounds__(256)
void pack_x_kernel(const float* __restrict__ x, u64* __restrict__ px) {
    int t = blockIdx.x * 256 + threadIdx.x;   // [0, 32*56*4*14) = 100352
    int w4   = t % 14;
    int r    = t / 14;
    int word = r & 3;
    int r2   = r >> 2;
    int h    = r2 % H;
    int n    = r2 / H;
    const float4* src = (const float4*)(x + ((size_t)(n*C_IN + word*64) * HW + h*W + w4*4));
    u64 b0 = 0, b1 = 0, b2 = 0, b3 = 0;
    #pragma unroll 8
    for (int j = 0; j < 64; ++j) {
        float4 v = src[(size_t)j * (HW/4)];
        b0 |= (u64)(__float_as_uint(v.x) >> 31) << j;
        b1 |= (u64)(__float_as_uint(v.y) >> 31) << j;
        b2 |= (u64)(__float_as_uint(v.z) >> 31) << j;
        b3 |= (u64)(__float_as_uint(v.w) >> 31) << j;
    }
    u64* dst = px + (((size_t)((n*H + h)*W + w4*4)) << 2) + word;
    dst[0] = b0; dst[4] = b1; dst[8] = b2; dst[12] = b3;
}

// ---------------------------------------------------------------------------
// Pack weights: pw[co][tap][word], tap = kh*3+kw, bit c%64 of word c/64.
// ---------------------------------------------------------------------------
__global__ __launch_bounds__(256)
void pack_w_kernel(const float* __restrict__ wt, u64* __restrict__ pw) {
    int t = blockIdx.x * 256 + threadIdx.x;   // [0, 256*9*4) = 9216
    int word = t & 3;
    int tap  = (t >> 2) % 9;
    int co   = t / 36;
    int kh = tap / 3, kw = tap % 3;
    u64 bits = 0;
    for (int j = 0; j < 64; ++j) {
        int c = word*64 + j;
        float v = wt[((size_t)(co*C_IN + c) * 9) + kh*3 + kw];
        bits |= (u64)(__float_as_uint(v) >> 31) << j;
    }
    pw[t] = bits;   // t == (co*9 + tap)*4 + word
}

// ---------------------------------------------------------------------------
// XNOR-popcount conv.
// R1 post-mortem: VGPR_Count=64 -> the 36 tap u64s (72 VGPRs) were STILL
// spilled; LLVM's occupancy heuristic targeted 8 waves/SIMD. Two fixes:
//   (1) amdgpu_waves_per_eu(4,4): hard 128-VGPR allocation target.
//   (2) output channels in 4 groups of 16, ONE live acc at a time:
//       peak pressure = 72 (x taps) + ~20 misc < 128 even if (1) misfires.
// Weights are wave-uniform -> s_load broadcast (SMEM pipe, free vs VALU).
// ---------------------------------------------------------------------------
__global__ __launch_bounds__(256)
__attribute__((amdgpu_waves_per_eu(4, 4)))
void conv_kernel(const u64* __restrict__ px, const u64* __restrict__ pw,
                 short* __restrict__ y) {
    int p = blockIdx.x * 256 + threadIdx.x;   // [0, 100352)
    int n = p / HW;
    int r = p % HW;
    int h = r / W;
    int w = r % W;
    int cobase = blockIdx.y * 64;

    int accbase = 0;   // 128 per invalid (padding) tap -> contributes 0 to y

#define LOADTAP(T, KH, KW)                                                  \
    u64 xa##T, xb##T, xc##T, xd##T; int m##T;                               \
    {                                                                       \
        int hh = h + (KH) - 1, ww = w + (KW) - 1;                           \
        bool ok = ((unsigned)hh < (unsigned)H) && ((unsigned)ww < (unsigned)W); \
        int hc = ok ? hh : 0, wc = ok ? ww : 0;                             \
        const u64* s = px + (((size_t)((n*H + hc)*W + wc)) << 2);           \
        xa##T = s[0]; xb##T = s[1]; xc##T = s[2]; xd##T = s[3];             \
        m##T = ok ? -1 : 0;                                                 \
        accbase += ok ? 0 : 128;                                            \
    }

    LOADTAP(0, 0, 0) LOADTAP(1, 0, 1) LOADTAP(2, 0, 2)
    LOADTAP(3, 1, 0) LOADTAP(4, 1, 1) LOADTAP(5, 1, 2)
    LOADTAP(6, 2, 0) LOADTAP(7, 2, 1) LOADTAP(8, 2, 2)
#undef LOADTAP

    const u64* wq = pw + (size_t)cobase * 36;
    short* yout = y + (size_t)n*CHW + (size_t)cobase*HW + r;

#define TAP(T, Q)                                                           \
        {                                                                   \
            int pc = __popcll(xa##T ^ (Q)[(T)*4+0])                         \
                   + __popcll(xb##T ^ (Q)[(T)*4+1])                         \
                   + __popcll(xc##T ^ (Q)[(T)*4+2])                         \
                   + __popcll(xd##T ^ (Q)[(T)*4+3]);                        \
            acc += pc & m##T;                                               \
        }
#define CI(I)                                                               \
        {                                                                   \
            const u64* q = qg + (I)*36;  /* wave-uniform */                 \
            int acc = accbase;                                              \
            TAP(0,q) TAP(1,q) TAP(2,q) TAP(3,q) TAP(4,q)                    \
            TAP(5,q) TAP(6,q) TAP(7,q) TAP(8,q)                             \
            yout[(size_t)(gbase + (I)) * HW] = (short)(2304 - 2*acc);       \
        }

    #pragma unroll 1
    for (int g = 0; g < 4; ++g) {
        int gbase = g * 16;
        const u64* qg = wq + (size_t)gbase * 36;
        CI(0)  CI(1)  CI(2)  CI(3)  CI(4)  CI(5)  CI(6)  CI(7)
        CI(8)  CI(9)  CI(10) CI(11) CI(12) CI(13) CI(14) CI(15)
    }
#undef CI
#undef TAP
}

// ---------------------------------------------------------------------------
// Stats pass: one block per (n,co) slab (3136 contiguous shorts), int4 loads
// (8 shorts), block-reduce, write per-slab partials (no atomics, no memset).
// ---------------------------------------------------------------------------
__global__ __launch_bounds__(256)
void stats_kernel(const short* __restrict__ y, long long* __restrict__ partials) {
    int slab = blockIdx.x;                    // n*256 + co
    const int4* ys = (const int4*)(y + (size_t)slab * HW);
    int s = 0, sq = 0;
    for (int i = threadIdx.x; i < HW/8; i += 256) {   // 392 int4 per slab
        int4 v = ys[i];
        int vv[4] = {v.x, v.y, v.z, v.w};
        #pragma unroll
        for (int k = 0; k < 4; ++k) {
            int lo = (short)(vv[k] & 0xFFFF);
            int hi = (short)(vv[k] >> 16);
            s  += lo + hi;
            sq += lo*lo + hi*hi;
        }
    }
    __shared__ int       rs[256];
    __shared__ long long rq[256];
    rs[threadIdx.x] = s;
    rq[threadIdx.x] = sq;
    __syncthreads();
    for (int off = 128; off > 0; off >>= 1) {
        if (threadIdx.x < off) {
            rs[threadIdx.x] += rs[threadIdx.x + off];
            rq[threadIdx.x] += rq[threadIdx.x + off];
        }
        __syncthreads();
    }
    if (threadIdx.x == 0) {
        partials[2*slab]   = rs[0];
        partials[2*slab+1] = rq[0];
    }
}

// ---------------------------------------------------------------------------
// Apply pass: one block per (n,co) slab. Reduce the 32 per-image partials of
// this channel (uniform scalar loads), compute a,b, vectorized normalize.
// ---------------------------------------------------------------------------
__global__ __launch_bounds__(256)
void apply_kernel(const short* __restrict__ y, const long long* __restrict__ partials,
                  const float* __restrict__ gamma, const float* __restrict__ beta,
                  float* __restrict__ out) {
    int slab = blockIdx.x;
    int co = slab & 255;
    long long S = 0, SS = 0;
    #pragma unroll 8
    for (int m = 0; m < N_IMG; ++m) {
        S  += partials[2*((m<<8) | co)];
        SS += partials[2*((m<<8) | co) + 1];
    }
    double mean = (double)S  * (1.0 / (double)NHW);
    double var  = (double)SS * (1.0 / (double)NHW) - mean*mean;
    float a = gamma[co] * rsqrtf((float)var + 1e-5f);
    float b = beta[co] - (float)mean * a;

    const int4* ys = (const int4*)(y + (size_t)slab * HW);
    float4*     os = (float4*)(out + (size_t)slab * HW);
    for (int i = threadIdx.x; i < HW/8; i += 256) {
        int4 v = ys[i];
        float4 f0, f1;
        f0.x = a * (float)((short)(v.x & 0xFFFF)) + b;
        f0.y = a * (float)((short)(v.x >> 16))    + b;
        f0.z = a * (float)((short)(v.y & 0xFFFF)) + b;
        f0.w = a * (float)((short)(v.y >> 16))    + b;
        f1.x = a * (float)((short)(v.z & 0xFFFF)) + b;
        f1.y = a * (float)((short)(v.z >> 16))    + b;
        f1.z = a * (float)((short)(v.w & 0xFFFF)) + b;
        f1.w = a * (float)((short)(v.w >> 16))    + b;
        os[2*i]   = f0;
        os[2*i+1] = f1;
    }
}

// ---------------------------------------------------------------------------
extern "C" void kernel_launch(void* const* d_in, const int* in_sizes, int n_in,
                              void* d_out, int out_size, void* d_ws, size_t ws_size,
                              hipStream_t stream) {
    const float* x     = (const float*)d_in[0];
    const float* wt    = (const float*)d_in[1];
    const float* gamma = (const float*)d_in[2];
    const float* beta  = (const float*)d_in[3];
    float* out = (float*)d_out;

    char* ws = (char*)d_ws;
    u64*   px = (u64*)ws;
    u64*   pw = (u64*)(ws + PX_BYTES);
    short* y  = (short*)(ws + PX_BYTES + PW_BYTES);
    long long* partials = (long long*)ws;   // overlaps px: px dead after conv

    hipLaunchKernelGGL(pack_x_kernel, dim3(100352/256), dim3(256), 0, stream, x, px);
    hipLaunchKernelGGL(pack_w_kernel, dim3(9216/256),   dim3(256), 0, stream, wt, pw);
    hipLaunchKernelGGL(conv_kernel,   dim3(392, 4),     dim3(256), 0, stream, px, pw, y);
    hipLaunchKernelGGL(stats_kernel,  dim3(8192),       dim3(256), 0, stream, y, partials);
    hipLaunchKernelGGL(apply_kernel,  dim3(8192),       dim3(256), 0, stream, y, partials, gamma, beta, out);
}